// Round 4
// baseline (643.442 us; speedup 1.0000x reference)
//
#include <hip/hip_runtime.h>

#define HH 512
#define WW 512
#define NPLANES 48              // B*C = 16*3
#define TILE 32
#define HALO 11
#define ITILE 54                // TILE + 2*HALO
#define IT_W 56                 // sIn/sTg row pitch (16B-aligned rows)
#define HB_W 36                 // hb row pitch: b128 writes balanced, scalar col-reads conflict-free
#define KSIZE 23
#define NBLK (16 * 16 * NPLANES)
#define C1V 1.0e-4f             // 0.01^2
#define C2V 9.0e-4f             // 0.03^2

// Horizontal pass, one source plane S: hb0 = conv_row(S), hb1 = conv_row(S*S).
__device__ __forceinline__ void hpass_sq(const float (*__restrict__ S)[IT_W],
                                         float (*__restrict__ hb0)[HB_W],
                                         float (*__restrict__ hb1)[HB_W],
                                         const float* __restrict__ sg, int tid)
{
    for (int t = tid; t < ITILE * (TILE / 4); t += 256) {
        int r = t >> 3;
        int cg = (t & 7) << 2;
        float wa[28], wa2[28];
        const float4* pa = (const float4*)&S[r][cg];
        #pragma unroll
        for (int q = 0; q < 7; ++q) {
            float4 v = pa[q];
            wa[4*q+0] = v.x; wa[4*q+1] = v.y; wa[4*q+2] = v.z; wa[4*q+3] = v.w;
        }
        #pragma unroll
        for (int q = 0; q < 28; ++q) wa2[q] = wa[q] * wa[q];
        float h0[4] = {0.f,0.f,0.f,0.f};
        float h1[4] = {0.f,0.f,0.f,0.f};
        #pragma unroll
        for (int j = 0; j < KSIZE; ++j) {
            float g = sg[j];
            #pragma unroll
            for (int i = 0; i < 4; ++i) {
                h0[i] += g * wa[j + i];
                h1[i] += g * wa2[j + i];
            }
        }
        *(float4*)&hb0[r][cg] = make_float4(h0[0], h0[1], h0[2], h0[3]);
        *(float4*)&hb1[r][cg] = make_float4(h1[0], h1[1], h1[2], h1[3]);
    }
}

// Horizontal pass, product plane: hb0 = conv_row(A*B).
__device__ __forceinline__ void hpass_prod(const float (*__restrict__ A)[IT_W],
                                           const float (*__restrict__ B)[IT_W],
                                           float (*__restrict__ hb0)[HB_W],
                                           const float* __restrict__ sg, int tid)
{
    for (int t = tid; t < ITILE * (TILE / 4); t += 256) {
        int r = t >> 3;
        int cg = (t & 7) << 2;
        float wab[28];
        const float4* pa = (const float4*)&A[r][cg];
        const float4* pb = (const float4*)&B[r][cg];
        #pragma unroll
        for (int q = 0; q < 7; ++q) {
            float4 va = pa[q];
            float4 vb = pb[q];
            wab[4*q+0] = va.x * vb.x; wab[4*q+1] = va.y * vb.y;
            wab[4*q+2] = va.z * vb.z; wab[4*q+3] = va.w * vb.w;
        }
        float h0[4] = {0.f,0.f,0.f,0.f};
        #pragma unroll
        for (int j = 0; j < KSIZE; ++j) {
            float g = sg[j];
            #pragma unroll
            for (int i = 0; i < 4; ++i) h0[i] += g * wab[j + i];
        }
        *(float4*)&hb0[r][cg] = make_float4(h0[0], h0[1], h0[2], h0[3]);
    }
}

// Vertical pass on one hb plane: thread = 4 consecutive rows x 1 col.
__device__ __forceinline__ void vpass(const float (*__restrict__ hb)[HB_W],
                                      const float* __restrict__ sg,
                                      int r0, int c, float out[4])
{
    float win[26];
    #pragma unroll
    for (int q = 0; q < 26; ++q) win[q] = hb[r0 + q][c];
    float a0 = 0.f, a1 = 0.f, a2 = 0.f, a3 = 0.f;
    #pragma unroll
    for (int j = 0; j < KSIZE; ++j) {
        float g = sg[j];
        a0 += g * win[j + 0];
        a1 += g * win[j + 1];
        a2 += g * win[j + 2];
        a3 += g * win[j + 3];
    }
    out[0] = a0; out[1] = a1; out[2] = a2; out[3] = a3;
}

__global__ __launch_bounds__(256) void ssim_main_kernel(
    const float* __restrict__ in, const float* __restrict__ tg,
    const float* __restrict__ w, float* __restrict__ partial)
{
    __shared__ __align__(16) float sIn[ITILE][IT_W];
    __shared__ __align__(16) float sTg[ITILE][IT_W];
    __shared__ __align__(16) float hb[2][ITILE][HB_W];
    __shared__ float sg[KSIZE];
    __shared__ float swsum[4];

    const int tid = threadIdx.x;

    // 1D gaussian taps = row sums of the (separable, normalized) 2D kernel.
    if (tid < KSIZE) {
        float s = 0.f;
        #pragma unroll
        for (int j = 0; j < KSIZE; ++j) s += w[tid * KSIZE + j];
        sg[tid] = s;
    }

    const int blk = blockIdx.x;
    const int plane = blk / 256;
    const int t2 = blk - plane * 256;        // 16x16 tiles
    const int x0 = (t2 & 15) * TILE - HALO;
    const int y0 = (t2 >> 4) * TILE - HALO;
    const float* __restrict__ inp = in + (size_t)plane * (HH * WW);
    const float* __restrict__ tgp = tg + (size_t)plane * (HH * WW);

    // ---- stage input tiles (zero-padded at image borders) ----
    for (int t = tid; t < ITILE * ITILE; t += 256) {
        int r = t / ITILE, c = t - r * ITILE;
        int gy = y0 + r, gx = x0 + c;
        bool ok = (gy >= 0) & (gy < HH) & (gx >= 0) & (gx < WW);
        int idx = gy * WW + gx;
        sIn[r][c] = ok ? inp[idx] : 0.f;
        sTg[r][c] = ok ? tgp[idx] : 0.f;
    }
    __syncthreads();

    const int c  = tid & 31;
    const int r0 = (tid >> 5) << 2;       // 0,4,...,28

    float vx[4], vt[4], vxx[4], vtt[4], vxt[4];

    // ---- phase A: {x, x^2} ----
    hpass_sq(sIn, hb[0], hb[1], sg, tid);
    __syncthreads();
    vpass(hb[0], sg, r0, c, vx);
    vpass(hb[1], sg, r0, c, vxx);
    __syncthreads();

    // ---- phase B: {t, t^2} ----
    hpass_sq(sTg, hb[0], hb[1], sg, tid);
    __syncthreads();
    vpass(hb[0], sg, r0, c, vt);
    vpass(hb[1], sg, r0, c, vtt);
    __syncthreads();

    // ---- phase C: {x*t} ----
    hpass_prod(sIn, sTg, hb[0], sg, tid);
    __syncthreads();
    vpass(hb[0], sg, r0, c, vxt);

    // ---- SSIM map + local sum ----
    float lsum = 0.f;
    #pragma unroll
    for (int rr = 0; rr < 4; ++rr) {
        float m1s = vx[rr] * vx[rr], m2s = vt[rr] * vt[rr], m12 = vx[rr] * vt[rr];
        float s1 = vxx[rr] - m1s, s2 = vtt[rr] - m2s, s12 = vxt[rr] - m12;
        float num = (2.f * m12 + C1V) * (2.f * s12 + C2V);
        float den = (m1s + m2s + C1V) * (s1 + s2 + C2V);
        lsum += num / den;
    }

    // ---- block reduction -> per-block partial ----
    #pragma unroll
    for (int off = 32; off > 0; off >>= 1)
        lsum += __shfl_down(lsum, off, 64);
    if ((tid & 63) == 0) swsum[tid >> 6] = lsum;
    __syncthreads();
    if (tid == 0)
        partial[blk] = swsum[0] + swsum[1] + swsum[2] + swsum[3];
}

__global__ __launch_bounds__(256) void ssim_final_kernel(
    const float* __restrict__ partial, float* __restrict__ out)
{
    __shared__ float swsum[4];
    const int tid = threadIdx.x;
    float s = 0.f;
    for (int i = tid; i < NBLK; i += 256) s += partial[i];
    #pragma unroll
    for (int off = 32; off > 0; off >>= 1)
        s += __shfl_down(s, off, 64);
    if ((tid & 63) == 0) swsum[tid >> 6] = s;
    __syncthreads();
    if (tid == 0)
        out[0] = 1.0f - (swsum[0] + swsum[1] + swsum[2] + swsum[3])
                        * (1.0f / ((float)NPLANES * HH * WW));
}

extern "C" void kernel_launch(void* const* d_in, const int* in_sizes, int n_in,
                              void* d_out, int out_size, void* d_ws, size_t ws_size,
                              hipStream_t stream) {
    const float* inp = (const float*)d_in[0];
    const float* tgt = (const float*)d_in[1];
    const float* wgt = (const float*)d_in[2];
    float* out = (float*)d_out;
    float* partial = (float*)d_ws;

    ssim_main_kernel<<<NBLK, 256, 0, stream>>>(inp, tgt, wgt, partial);
    ssim_final_kernel<<<1, 256, 0, stream>>>(partial, out);
}

// Round 5
// 304.145 us; speedup vs baseline: 2.1156x; 2.1156x over previous
//
#include <hip/hip_runtime.h>

#define HH 512
#define WW 512
#define NPLANES 48              // B*C = 16*3
#define TILE 32
#define HALO 11
#define ITILE 54                // staged rows (and used cols)
#define SIN_PD 28               // staged row pitch in dwords (56 bf16)
#define HB_PD 30                // hbT per-column pitch in dwords (60 bf16 rows, 54 used)
#define KSIZE 23
#define NBLK (16 * 16 * NPLANES)
#define C1V 1.0e-4f             // 0.01^2
#define C2V 9.0e-4f             // 0.03^2

__device__ __forceinline__ unsigned f2bf(float x) {   // fp32 -> bf16 (RNE)
    unsigned u = __float_as_uint(x);
    return (u + 0x7fffu + ((u >> 16) & 1u)) >> 16;
}
__device__ __forceinline__ float bflo(unsigned u) { return __uint_as_float(u << 16); }
__device__ __forceinline__ float bfhi(unsigned u) { return __uint_as_float(u & 0xffff0000u); }

__global__ __launch_bounds__(256, 4) void ssim_main_kernel(
    const float* __restrict__ in, const float* __restrict__ tg,
    const float* __restrict__ w, float* __restrict__ partial)
{
    __shared__ unsigned sA[ITILE * SIN_PD];       // 6048 B, bf16 pairs
    __shared__ unsigned sB[ITILE * SIN_PD];       // 6048 B
    __shared__ unsigned hbT[5][TILE * HB_PD];     // 19200 B, [ch][c*30 + r/2], rows packed in pairs
    __shared__ float sg[KSIZE];
    __shared__ float swsum[4];

    const int tid = threadIdx.x;

    // 1D gaussian taps = row sums of the (separable, normalized) 2D kernel.
    if (tid < KSIZE) {
        float s = 0.f;
        #pragma unroll
        for (int j = 0; j < KSIZE; ++j) s += w[tid * KSIZE + j];
        sg[tid] = s;
    }

    const int blk = blockIdx.x;
    const int plane = blk >> 8;
    const int t2 = blk & 255;
    const int x0 = (t2 & 15) * TILE - HALO;
    const int y0 = (t2 >> 4) * TILE - HALO;
    const float* __restrict__ inp = in + (size_t)plane * (HH * WW);
    const float* __restrict__ tgp = tg + (size_t)plane * (HH * WW);

    // ---- stage input tiles as bf16 pairs (zero-padded at borders) ----
    for (int t = tid; t < ITILE * 27; t += 256) {
        int r = t / 27, cd = t - r * 27;
        int gy = y0 + r, gx = x0 + cd * 2;
        float a0 = 0.f, a1 = 0.f, b0 = 0.f, b1 = 0.f;
        if (gy >= 0 && gy < HH) {
            const float* ri = inp + gy * WW;
            const float* rt = tgp + gy * WW;
            if ((unsigned)gx < (unsigned)WW)       { a0 = ri[gx];     b0 = rt[gx]; }
            if ((unsigned)(gx + 1) < (unsigned)WW) { a1 = ri[gx + 1]; b1 = rt[gx + 1]; }
        }
        sA[r * SIN_PD + cd] = f2bf(a0) | (f2bf(a1) << 16);
        sB[r * SIN_PD + cd] = f2bf(b0) | (f2bf(b1) << 16);
    }
    __syncthreads();

    // ---- horizontal pass: 27 row-pairs x 8 col-groups(4) = 216 tasks ----
    if (tid < 216) {
        const int rp  = tid >> 3;            // row pair 0..26
        const int cg4 = (tid & 7) << 2;      // col group start 0,4,...,28
        const int cdw = cg4 >> 1;            // even dword offset into row

        unsigned pk[10];                     // row0 results, bf16-packed (2 cols/uint)
        #pragma unroll
        for (int rr = 0; rr < 2; ++rr) {
            const int r = rp * 2 + rr;
            float A[28], B[28];
            const uint2* pa = (const uint2*)&sA[r * SIN_PD + cdw];
            const uint2* pb = (const uint2*)&sB[r * SIN_PD + cdw];
            #pragma unroll
            for (int k = 0; k < 7; ++k) {
                uint2 va = pa[k], vb = pb[k];
                A[4*k+0] = bflo(va.x); A[4*k+1] = bfhi(va.x);
                A[4*k+2] = bflo(va.y); A[4*k+3] = bfhi(va.y);
                B[4*k+0] = bflo(vb.x); B[4*k+1] = bfhi(vb.x);
                B[4*k+2] = bflo(vb.y); B[4*k+3] = bfhi(vb.y);
            }
            float hx[4]  = {0,0,0,0}, ht[4]  = {0,0,0,0};
            float hxx[4] = {0,0,0,0}, htt[4] = {0,0,0,0}, hxt[4] = {0,0,0,0};
            #pragma unroll
            for (int j = 0; j < KSIZE; ++j) {
                float g = sg[j];
                #pragma unroll
                for (int i = 0; i < 4; ++i) {
                    float a = A[j + i], b = B[j + i];
                    float ga = g * a, gb = g * b;
                    hx[i]  += ga;      ht[i]  += gb;
                    hxx[i] += ga * a;  htt[i] += gb * b;  hxt[i] += ga * b;
                }
            }
            if (rr == 0) {
                #pragma unroll
                for (int p = 0; p < 2; ++p) {
                    pk[0*2+p] = f2bf(hx[2*p])  | (f2bf(hx[2*p+1])  << 16);
                    pk[1*2+p] = f2bf(ht[2*p])  | (f2bf(ht[2*p+1])  << 16);
                    pk[2*2+p] = f2bf(hxx[2*p]) | (f2bf(hxx[2*p+1]) << 16);
                    pk[3*2+p] = f2bf(htt[2*p]) | (f2bf(htt[2*p+1]) << 16);
                    pk[4*2+p] = f2bf(hxt[2*p]) | (f2bf(hxt[2*p+1]) << 16);
                }
            } else {
                float* chp[5] = {hx, ht, hxx, htt, hxt};
                #pragma unroll
                for (int ch = 0; ch < 5; ++ch) {
                    #pragma unroll
                    for (int i = 0; i < 4; ++i) {
                        unsigned lo = (pk[ch*2 + (i >> 1)] >> (16 * (i & 1))) & 0xffffu;
                        unsigned hi = f2bf(chp[ch][i]) << 16;
                        hbT[ch][(cg4 + i) * HB_PD + rp] = hi | lo;   // rows (2rp,2rp+1)
                    }
                }
            }
        }
    }
    __syncthreads();

    // ---- vertical pass: thread = 4 consecutive rows x 1 col ----
    const int c  = tid & 31;
    const int r0 = (tid >> 5) << 2;                 // 0,4,...,28
    const int bdw = c * HB_PD + (r0 >> 1);          // even dword base

    float res[5][4];
    #pragma unroll
    for (int ch = 0; ch < 5; ++ch) {
        unsigned d[13];
        const uint2* p = (const uint2*)&hbT[ch][bdw];
        #pragma unroll
        for (int k = 0; k < 6; ++k) { uint2 v = p[k]; d[2*k] = v.x; d[2*k+1] = v.y; }
        d[12] = hbT[ch][bdw + 12];
        float win[26];
        #pragma unroll
        for (int k = 0; k < 13; ++k) { win[2*k] = bflo(d[k]); win[2*k+1] = bfhi(d[k]); }
        float a0 = 0.f, a1 = 0.f, a2 = 0.f, a3 = 0.f;
        #pragma unroll
        for (int j = 0; j < KSIZE; ++j) {
            float g = sg[j];
            a0 += g * win[j + 0];
            a1 += g * win[j + 1];
            a2 += g * win[j + 2];
            a3 += g * win[j + 3];
        }
        res[ch][0] = a0; res[ch][1] = a1; res[ch][2] = a2; res[ch][3] = a3;
    }

    // ---- SSIM map + local sum ----
    float lsum = 0.f;
    #pragma unroll
    for (int rr = 0; rr < 4; ++rr) {
        float vx = res[0][rr], vt = res[1][rr];
        float vxx = res[2][rr], vtt = res[3][rr], vxt = res[4][rr];
        float m1s = vx * vx, m2s = vt * vt, m12 = vx * vt;
        float s1 = vxx - m1s, s2 = vtt - m2s, s12 = vxt - m12;
        float num = (2.f * m12 + C1V) * (2.f * s12 + C2V);
        float den = (m1s + m2s + C1V) * (s1 + s2 + C2V);
        lsum += num * __builtin_amdgcn_rcpf(den);   // den > 0 always
    }

    // ---- block reduction -> per-block partial ----
    #pragma unroll
    for (int off = 32; off > 0; off >>= 1)
        lsum += __shfl_down(lsum, off, 64);
    if ((tid & 63) == 0) swsum[tid >> 6] = lsum;
    __syncthreads();
    if (tid == 0)
        partial[blk] = swsum[0] + swsum[1] + swsum[2] + swsum[3];
}

__global__ __launch_bounds__(256) void ssim_final_kernel(
    const float* __restrict__ partial, float* __restrict__ out)
{
    __shared__ float swsum[4];
    const int tid = threadIdx.x;
    float s = 0.f;
    for (int i = tid; i < NBLK; i += 256) s += partial[i];
    #pragma unroll
    for (int off = 32; off > 0; off >>= 1)
        s += __shfl_down(s, off, 64);
    if ((tid & 63) == 0) swsum[tid >> 6] = s;
    __syncthreads();
    if (tid == 0)
        out[0] = 1.0f - (swsum[0] + swsum[1] + swsum[2] + swsum[3])
                        * (1.0f / ((float)NPLANES * HH * WW));
}

extern "C" void kernel_launch(void* const* d_in, const int* in_sizes, int n_in,
                              void* d_out, int out_size, void* d_ws, size_t ws_size,
                              hipStream_t stream) {
    const float* inp = (const float*)d_in[0];
    const float* tgt = (const float*)d_in[1];
    const float* wgt = (const float*)d_in[2];
    float* out = (float*)d_out;
    float* partial = (float*)d_ws;

    ssim_main_kernel<<<NBLK, 256, 0, stream>>>(inp, tgt, wgt, partial);
    ssim_final_kernel<<<1, 256, 0, stream>>>(partial, out);
}

// Round 6
// 279.849 us; speedup vs baseline: 2.2992x; 1.0868x over previous
//
#include <hip/hip_runtime.h>

#define HH 512
#define WW 512
#define NPLANES 48              // B*C = 16*3
#define TILE 32
#define HALO 11
#define ITILE 54                // staged rows / used cols
#define SPITCH 28               // staged row pitch in bf16-PAIRS (dwords); 27 used
#define HPITCH 60               // hbT per-column pitch in bf16 elems; rows 0..53 used
#define KSIZE 23
#define NBLK (16 * 16 * NPLANES)
#define C1V 1.0e-4f             // 0.01^2
#define C2V 9.0e-4f             // 0.03^2

__device__ __forceinline__ unsigned f2bf(float x) {   // fp32 -> bf16 (RNE), finite inputs
    unsigned u = __float_as_uint(x);
    return (u + 0x7fffu + ((u >> 16) & 1u)) >> 16;
}
__device__ __forceinline__ float bflo(unsigned u) { return __uint_as_float(u << 16); }
__device__ __forceinline__ float bfhi(unsigned u) { return __uint_as_float(u & 0xffff0000u); }

// taps[j] = sum_k w2d[j][k]  (exact separable 1D gaussian, since kernel = g g^T and sum g = 1)
__global__ void ssim_prep_kernel(const float* __restrict__ w, float* __restrict__ taps) {
    int j = threadIdx.x;
    if (j < KSIZE) {
        float s = 0.f;
        #pragma unroll
        for (int k = 0; k < KSIZE; ++k) s += w[j * KSIZE + k];
        taps[j] = s;
    }
}

__global__ __launch_bounds__(256, 4) void ssim_main_kernel(
    const float* __restrict__ in, const float* __restrict__ tg,
    const float* __restrict__ taps, float* __restrict__ partial)
{
    __shared__ unsigned sA[ITILE * SPITCH];        // bf16 pairs, 6048 B
    __shared__ unsigned sB[ITILE * SPITCH];        // 6048 B
    __shared__ unsigned short hbT[5][TILE * HPITCH]; // bf16, [ch][c*60 + r], 19200 B
    __shared__ float sg[KSIZE];
    __shared__ float swsum[4];

    const int tid = threadIdx.x;

    if (tid < KSIZE) sg[tid] = taps[tid];

    const int blk = blockIdx.x;
    const int plane = blk >> 8;
    const int t2 = blk & 255;
    const int x0 = (t2 & 15) * TILE - HALO;
    const int y0 = (t2 >> 4) * TILE - HALO;
    const float* __restrict__ inp = in + (size_t)plane * (HH * WW);
    const float* __restrict__ tgp = tg + (size_t)plane * (HH * WW);

    // ---- stage input tiles as bf16 pairs (zero-padded at borders) ----
    for (int t = tid; t < ITILE * 27; t += 256) {
        int r = t / 27, cd = t - r * 27;
        int gy = y0 + r, gx = x0 + cd * 2;
        float a0 = 0.f, a1 = 0.f, b0 = 0.f, b1 = 0.f;
        if (gy >= 0 && gy < HH) {
            const float* ri = inp + gy * WW;
            const float* rt = tgp + gy * WW;
            if ((unsigned)gx < (unsigned)WW)       { a0 = ri[gx];     b0 = rt[gx]; }
            if ((unsigned)(gx + 1) < (unsigned)WW) { a1 = ri[gx + 1]; b1 = rt[gx + 1]; }
        }
        sA[r * SPITCH + cd] = f2bf(a0) | (f2bf(a1) << 16);
        sB[r * SPITCH + cd] = f2bf(b0) | (f2bf(b1) << 16);
    }
    __syncthreads();

    // ---- horizontal pass: 54 rows x 8 col-groups(4) = 432 tasks, 1 row each ----
    for (int t = tid; t < ITILE * 8; t += 256) {
        const int r   = t >> 3;
        const int cg4 = (t & 7) << 2;        // 0,4,...,28
        const int cdw = cg4 >> 1;            // even dword offset

        float A[28], B[28];
        const uint2* pa = (const uint2*)&sA[r * SPITCH + cdw];
        const uint2* pb = (const uint2*)&sB[r * SPITCH + cdw];
        #pragma unroll
        for (int k = 0; k < 7; ++k) {
            uint2 va = pa[k], vb = pb[k];
            A[4*k+0] = bflo(va.x); A[4*k+1] = bfhi(va.x);
            A[4*k+2] = bflo(va.y); A[4*k+3] = bfhi(va.y);
            B[4*k+0] = bflo(vb.x); B[4*k+1] = bfhi(vb.x);
            B[4*k+2] = bflo(vb.y); B[4*k+3] = bfhi(vb.y);
        }
        float hx[4]  = {0,0,0,0}, ht[4]  = {0,0,0,0};
        float hxx[4] = {0,0,0,0}, htt[4] = {0,0,0,0}, hxt[4] = {0,0,0,0};
        #pragma unroll
        for (int j = 0; j < KSIZE; ++j) {
            float g = sg[j];
            #pragma unroll
            for (int i = 0; i < 4; ++i) {
                float a = A[j + i], b = B[j + i];
                float ga = g * a, gb = g * b;
                hx[i]  += ga;      ht[i]  += gb;
                hxx[i] += ga * a;  htt[i] += gb * b;  hxt[i] += ga * b;
            }
        }
        #pragma unroll
        for (int i = 0; i < 4; ++i) {
            const int base = (cg4 + i) * HPITCH + r;
            hbT[0][base] = (unsigned short)f2bf(hx[i]);
            hbT[1][base] = (unsigned short)f2bf(ht[i]);
            hbT[2][base] = (unsigned short)f2bf(hxx[i]);
            hbT[3][base] = (unsigned short)f2bf(htt[i]);
            hbT[4][base] = (unsigned short)f2bf(hxt[i]);
        }
    }
    __syncthreads();

    // ---- vertical pass: thread = 4 consecutive rows x 1 col ----
    const int c  = tid & 31;
    const int r0 = (tid >> 5) << 2;                 // 0,4,...,28

    float res[5][4];
    #pragma unroll
    for (int ch = 0; ch < 5; ++ch) {
        unsigned d[13];
        const uint2* p = (const uint2*)&hbT[ch][c * HPITCH + r0]; // 8B-aligned
        #pragma unroll
        for (int k = 0; k < 6; ++k) { uint2 v = p[k]; d[2*k] = v.x; d[2*k+1] = v.y; }
        d[12] = *(const unsigned*)&hbT[ch][c * HPITCH + r0 + 24];
        float win[26];
        #pragma unroll
        for (int k = 0; k < 13; ++k) { win[2*k] = bflo(d[k]); win[2*k+1] = bfhi(d[k]); }
        float a0 = 0.f, a1 = 0.f, a2 = 0.f, a3 = 0.f;
        #pragma unroll
        for (int j = 0; j < KSIZE; ++j) {
            float g = sg[j];
            a0 += g * win[j + 0];
            a1 += g * win[j + 1];
            a2 += g * win[j + 2];
            a3 += g * win[j + 3];
        }
        res[ch][0] = a0; res[ch][1] = a1; res[ch][2] = a2; res[ch][3] = a3;
    }

    // ---- SSIM map + local sum ----
    float lsum = 0.f;
    #pragma unroll
    for (int rr = 0; rr < 4; ++rr) {
        float vx = res[0][rr], vt = res[1][rr];
        float vxx = res[2][rr], vtt = res[3][rr], vxt = res[4][rr];
        float m1s = vx * vx, m2s = vt * vt, m12 = vx * vt;
        float s1 = vxx - m1s, s2 = vtt - m2s, s12 = vxt - m12;
        float num = (2.f * m12 + C1V) * (2.f * s12 + C2V);
        float den = (m1s + m2s + C1V) * (s1 + s2 + C2V);
        lsum += num * __builtin_amdgcn_rcpf(den);   // den > 0 always
    }

    // ---- block reduction -> per-block partial ----
    #pragma unroll
    for (int off = 32; off > 0; off >>= 1)
        lsum += __shfl_down(lsum, off, 64);
    if ((tid & 63) == 0) swsum[tid >> 6] = lsum;
    __syncthreads();
    if (tid == 0)
        partial[blk] = swsum[0] + swsum[1] + swsum[2] + swsum[3];
}

__global__ __launch_bounds__(256) void ssim_final_kernel(
    const float* __restrict__ partial, float* __restrict__ out)
{
    __shared__ float swsum[4];
    const int tid = threadIdx.x;
    float s = 0.f;
    for (int i = tid; i < NBLK; i += 256) s += partial[i];
    #pragma unroll
    for (int off = 32; off > 0; off >>= 1)
        s += __shfl_down(s, off, 64);
    if ((tid & 63) == 0) swsum[tid >> 6] = s;
    __syncthreads();
    if (tid == 0)
        out[0] = 1.0f - (swsum[0] + swsum[1] + swsum[2] + swsum[3])
                        * (1.0f / ((float)NPLANES * HH * WW));
}

extern "C" void kernel_launch(void* const* d_in, const int* in_sizes, int n_in,
                              void* d_out, int out_size, void* d_ws, size_t ws_size,
                              hipStream_t stream) {
    const float* inp = (const float*)d_in[0];
    const float* tgt = (const float*)d_in[1];
    const float* wgt = (const float*)d_in[2];
    float* out = (float*)d_out;
    float* taps = (float*)d_ws;            // [0,23)
    float* partial = (float*)d_ws + 32;    // [32, 32+NBLK)

    ssim_prep_kernel<<<1, 64, 0, stream>>>(wgt, taps);
    ssim_main_kernel<<<NBLK, 256, 0, stream>>>(inp, tgt, taps, partial);
    ssim_final_kernel<<<1, 256, 0, stream>>>(partial, out);
}

// Round 7
// 276.192 us; speedup vs baseline: 2.3297x; 1.0132x over previous
//
#include <hip/hip_runtime.h>

typedef float f32x4 __attribute__((ext_vector_type(4)));
typedef short bf16x8 __attribute__((ext_vector_type(8)));

#define HH 512
#define WW 512
#define NPLANES 48              // B*C = 16*3
#define TILE 32
#define HALO 11
#define KSIZE 23
#define NBLK (16 * 16 * NPLANES)
#define C1V 1.0e-4f             // 0.01^2
#define C2V 9.0e-4f             // 0.03^2

// LDS layout (ushort indices). Single array so overflow reads of padded
// M-rows (54..63) land in deterministic, finite, already-written regions:
// sA rows 54..63 -> PAD (zeroed); sB rows 54..63 -> sA (staged data).
// All such junk is multiplied by exact zeros in G (k-r outside [0,23)).
#define SB_O   0                // 54*72 ushorts
#define SA_O   3888
#define PAD_O  7776             // 720 ushorts, zero-filled
#define HB_O   8496             // 5 * 2304
#define HB_CH  2304             // 32 cols * 72 pitch
#define SPITCH 72               // bf16 pitch: 16B-aligned rows, bank-spread
#define LDS_TOT 20016           // 40032 B -> 4 blocks/CU

__device__ __forceinline__ unsigned f2bf(float x) {   // fp32 -> bf16 bits (RNE)
    unsigned u = __float_as_uint(x);
    return (u + 0x7fffu + ((u >> 16) & 1u)) >> 16;
}

// elementwise bf16 product of two bf16-pair dwords (fp32 exact mul, RNE round)
__device__ __forceinline__ unsigned bfmul2(unsigned a, unsigned b) {
    float al = __uint_as_float(a << 16), ah = __uint_as_float(a & 0xffff0000u);
    float bl = __uint_as_float(b << 16), bh = __uint_as_float(b & 0xffff0000u);
    float pl = al * bl, ph = ah * bh;
    unsigned uh = __float_as_uint(ph);
    unsigned hi = (uh + 0x7fffu + ((uh >> 16) & 1u)) & 0xffff0000u;
    return f2bf(pl) | hi;
}

__device__ __forceinline__ uint4 bfmul4(uint4 a, uint4 b) {
    uint4 r;
    r.x = bfmul2(a.x, b.x); r.y = bfmul2(a.y, b.y);
    r.z = bfmul2(a.z, b.z); r.w = bfmul2(a.w, b.w);
    return r;
}

__device__ __forceinline__ f32x4 mfma16(uint4 a, uint4 b, f32x4 c) {
    union { uint4 u; bf16x8 h; } ua, ub;
    ua.u = a; ub.u = b;
    return __builtin_amdgcn_mfma_f32_16x16x32_bf16(ua.h, ub.h, c, 0, 0, 0);
}

// Build G[32][64] bf16: G[r][k] = g[k-r] for 0<=k-r<23 else 0.
// Serves as B-operand (h-pass, indexed by out-col) and A-operand (v-pass, by out-row).
__global__ void ssim_prep_kernel(const float* __restrict__ w, unsigned short* __restrict__ G) {
    __shared__ float sg[KSIZE];
    const int tid = threadIdx.x;
    if (tid < KSIZE) {
        float s = 0.f;
        #pragma unroll
        for (int k = 0; k < KSIZE; ++k) s += w[tid * KSIZE + k];
        sg[tid] = s;     // 1D taps = row sums of separable normalized 2D kernel (exact)
    }
    __syncthreads();
    for (int t = tid; t < 32 * 64; t += 256) {
        int r = t >> 6, k = t & 63, d = k - r;
        unsigned short v = 0;
        if (d >= 0 && d < KSIZE) v = (unsigned short)f2bf(sg[d]);
        G[t] = v;
    }
}

__global__ __launch_bounds__(256, 4) void ssim_main_kernel(
    const float* __restrict__ in, const float* __restrict__ tg,
    const unsigned short* __restrict__ G, float* __restrict__ partial)
{
    __shared__ __align__(16) unsigned short lds[LDS_TOT];
    __shared__ float swsum[4];

    const int tid = threadIdx.x;
    const int wave = tid >> 6, lane = tid & 63;
    const int m = lane & 15, q = lane >> 4;

    // Hoisted tap fragments Gf[nc][ks]: lane holds G[nc*16+m][ks*32+q*8 .. +7].
    uint4 Gf[2][2];
    #pragma unroll
    for (int nc = 0; nc < 2; ++nc)
        #pragma unroll
        for (int ks = 0; ks < 2; ++ks)
            Gf[nc][ks] = *(const uint4*)(G + (nc * 16 + m) * 64 + ks * 32 + q * 8);

    const int blk = blockIdx.x;
    const int plane = blk >> 8;
    const int t2 = blk & 255;
    const int x0 = (t2 & 15) * TILE - HALO;
    const int y0 = (t2 >> 4) * TILE - HALO;
    const float* __restrict__ inp = in + (size_t)plane * (HH * WW);
    const float* __restrict__ tgp = tg + (size_t)plane * (HH * WW);

    unsigned* ldsw = (unsigned*)lds;
    for (int t = tid; t < 360; t += 256) ldsw[(PAD_O >> 1) + t] = 0;

    // ---- stage 54 rows x 64 cols as bf16 pairs (zero outside image) ----
    for (int t = tid; t < 54 * 32; t += 256) {
        int r = t >> 5, cd = t & 31;
        int gy = y0 + r, gx = x0 + cd * 2;
        float a0 = 0.f, a1 = 0.f, b0 = 0.f, b1 = 0.f;
        if (gy >= 0 && gy < HH) {
            const float* ri = inp + gy * WW;
            const float* rt = tgp + gy * WW;
            if ((unsigned)gx < (unsigned)WW)       { a0 = ri[gx];     b0 = rt[gx]; }
            if ((unsigned)(gx + 1) < (unsigned)WW) { a1 = ri[gx + 1]; b1 = rt[gx + 1]; }
        }
        ldsw[(SA_O >> 1) + r * 36 + cd] = f2bf(a0) | (f2bf(a1) << 16);
        ldsw[(SB_O >> 1) + r * 36 + cd] = f2bf(b0) | (f2bf(b1) << 16);
    }
    __syncthreads();

    // ---- h-pass (MFMA): wave handles M-tile `wave` (image rows wave*16..+15) ----
    // hb[r][c] = sum_k S[r][k] * G[c][k]  (G zero-padded handles K=54->64)
    f32x4 acc[5][2];
    const f32x4 zz = {0.f, 0.f, 0.f, 0.f};
    #pragma unroll
    for (int ch = 0; ch < 5; ++ch) { acc[ch][0] = zz; acc[ch][1] = zz; }

    #pragma unroll
    for (int ks = 0; ks < 2; ++ks) {
        const int off = (wave * 16 + m) * SPITCH + ks * 32 + q * 8;
        uint4 ua = *(const uint4*)&lds[SA_O + off];
        uint4 ub = *(const uint4*)&lds[SB_O + off];
        uint4 uaa = bfmul4(ua, ua);
        uint4 ubb = bfmul4(ub, ub);
        uint4 uab = bfmul4(ua, ub);
        #pragma unroll
        for (int nc = 0; nc < 2; ++nc) {
            acc[0][nc] = mfma16(ua,  Gf[nc][ks], acc[0][nc]);
            acc[1][nc] = mfma16(ub,  Gf[nc][ks], acc[1][nc]);
            acc[2][nc] = mfma16(uaa, Gf[nc][ks], acc[2][nc]);
            acc[3][nc] = mfma16(ubb, Gf[nc][ks], acc[3][nc]);
            acc[4][nc] = mfma16(uab, Gf[nc][ks], acc[4][nc]);
        }
    }
    // D frag: col = lane&15 (+nc*16), row = q*4 + reg (+wave*16). Store hbT[ch][col][row] bf16.
    #pragma unroll
    for (int ch = 0; ch < 5; ++ch)
        #pragma unroll
        for (int nc = 0; nc < 2; ++nc) {
            f32x4 a = acc[ch][nc];
            uint2 pk;
            pk.x = f2bf(a[0]) | (f2bf(a[1]) << 16);
            pk.y = f2bf(a[2]) | (f2bf(a[3]) << 16);
            *(uint2*)&lds[HB_O + ch * HB_CH + (nc * 16 + m) * SPITCH + wave * 16 + q * 4] = pk;
        }
    __syncthreads();

    // ---- v-pass (MFMA): wave = output quadrant (mrow, nc2) ----
    // out[r][c] = sum_k G[r][k] * hb[k][c]; junk hb rows 54..63 hit G zeros.
    const int mrow = wave >> 1, nc2 = wave & 1;
    f32x4 av[5];
    #pragma unroll
    for (int ch = 0; ch < 5; ++ch) av[ch] = zz;

    #pragma unroll
    for (int ks = 0; ks < 2; ++ks)
        #pragma unroll
        for (int ch = 0; ch < 5; ++ch) {
            uint4 ub = *(const uint4*)&lds[HB_O + ch * HB_CH + (nc2 * 16 + m) * SPITCH + ks * 32 + q * 8];
            av[ch] = mfma16(Gf[mrow][ks], ub, av[ch]);
        }

    // ---- SSIM map on 4 px/lane + reduction ----
    float lsum = 0.f;
    #pragma unroll
    for (int i = 0; i < 4; ++i) {
        float vx = av[0][i], vt = av[1][i];
        float vxx = av[2][i], vtt = av[3][i], vxt = av[4][i];
        float m1s = vx * vx, m2s = vt * vt, m12 = vx * vt;
        float s1 = vxx - m1s, s2 = vtt - m2s, s12 = vxt - m12;
        float num = (2.f * m12 + C1V) * (2.f * s12 + C2V);
        float den = (m1s + m2s + C1V) * (s1 + s2 + C2V);
        lsum += num * __builtin_amdgcn_rcpf(den);   // den > 0 always
    }
    #pragma unroll
    for (int off = 32; off > 0; off >>= 1)
        lsum += __shfl_down(lsum, off, 64);
    if (lane == 0) swsum[wave] = lsum;
    __syncthreads();
    if (tid == 0)
        partial[blk] = swsum[0] + swsum[1] + swsum[2] + swsum[3];
}

__global__ __launch_bounds__(256) void ssim_final_kernel(
    const float* __restrict__ partial, float* __restrict__ out)
{
    __shared__ float swsum[4];
    const int tid = threadIdx.x;
    float s = 0.f;
    for (int i = tid; i < NBLK; i += 256) s += partial[i];
    #pragma unroll
    for (int off = 32; off > 0; off >>= 1)
        s += __shfl_down(s, off, 64);
    if ((tid & 63) == 0) swsum[tid >> 6] = s;
    __syncthreads();
    if (tid == 0)
        out[0] = 1.0f - (swsum[0] + swsum[1] + swsum[2] + swsum[3])
                        * (1.0f / ((float)NPLANES * HH * WW));
}

extern "C" void kernel_launch(void* const* d_in, const int* in_sizes, int n_in,
                              void* d_out, int out_size, void* d_ws, size_t ws_size,
                              hipStream_t stream) {
    const float* inp = (const float*)d_in[0];
    const float* tgt = (const float*)d_in[1];
    const float* wgt = (const float*)d_in[2];
    float* out = (float*)d_out;
    unsigned short* G = (unsigned short*)d_ws;              // 32*64 bf16 = 4 KB
    float* partial = (float*)((char*)d_ws + 4096);          // NBLK floats

    ssim_prep_kernel<<<1, 256, 0, stream>>>(wgt, G);
    ssim_main_kernel<<<NBLK, 256, 0, stream>>>(inp, tgt, G, partial);
    ssim_final_kernel<<<1, 256, 0, stream>>>(partial, out);
}

// Round 8
// 213.004 us; speedup vs baseline: 3.0208x; 1.2967x over previous
//
#include <hip/hip_runtime.h>

typedef float f32x4 __attribute__((ext_vector_type(4)));
typedef short bf16x8 __attribute__((ext_vector_type(8)));

#define HH 512
#define WW 512
#define NPLANES 48              // B*C = 16*3
#define TILE 32
#define HALO 11
#define KSIZE 23
#define NBLK (16 * 16 * NPLANES)
#define C1V 1.0e-4f             // 0.01^2
#define C2V 9.0e-4f             // 0.03^2

// LDS layout (ushort indices). Overflow reads of padded M-rows (54..63):
// sB rows 54..63 -> sA rows 0..9 (finite staged bf16); sA rows 54..63 ->
// G region (finite bf16 taps). All junk multiplied by exact zeros in G.
#define SB_O   0                // 54 rows * 72
#define SA_O   3888             // 54 rows * 72
#define G_O    7776             // 32 rows * 64, xor-swizzled
#define HB_O   9824             // 5 ch * 32 cols * 64, xor-swizzled
#define HB_CH  2048
#define SPITCH 72               // staging pitch (16B-aligned rows, bank-spread)
#define LDS_TOT 20064           // 40128 B -> 4 blocks/CU

// XOR bank swizzle for pitch-64 regions; preserves 16B blocks (bits 0..2).
#define SWZ(rho, k) ((k) ^ (((rho) & 7) << 3))

__device__ __forceinline__ unsigned f2bf(float x) {   // fp32 -> bf16 bits (RNE)
    unsigned u = __float_as_uint(x);
    return (u + 0x7fffu + ((u >> 16) & 1u)) >> 16;
}

// elementwise bf16 product of two bf16-pair dwords (fp32 exact mul, RNE round)
__device__ __forceinline__ unsigned bfmul2(unsigned a, unsigned b) {
    float al = __uint_as_float(a << 16), ah = __uint_as_float(a & 0xffff0000u);
    float bl = __uint_as_float(b << 16), bh = __uint_as_float(b & 0xffff0000u);
    float pl = al * bl, ph = ah * bh;
    unsigned uh = __float_as_uint(ph);
    unsigned hi = (uh + 0x7fffu + ((uh >> 16) & 1u)) & 0xffff0000u;
    return f2bf(pl) | hi;
}

__device__ __forceinline__ uint4 bfmul4(uint4 a, uint4 b) {
    uint4 r;
    r.x = bfmul2(a.x, b.x); r.y = bfmul2(a.y, b.y);
    r.z = bfmul2(a.z, b.z); r.w = bfmul2(a.w, b.w);
    return r;
}

__device__ __forceinline__ f32x4 mfma16(uint4 a, uint4 b, f32x4 c) {
    union { uint4 u; bf16x8 h; } ua, ub;
    ua.u = a; ub.u = b;
    return __builtin_amdgcn_mfma_f32_16x16x32_bf16(ua.h, ub.h, c, 0, 0, 0);
}

// Build G[32][64] bf16 (row-major, plain): G[r][k] = g[k-r] for 0<=k-r<23 else 0.
__global__ void ssim_prep_kernel(const float* __restrict__ w, unsigned short* __restrict__ G) {
    __shared__ float sg[KSIZE];
    const int tid = threadIdx.x;
    if (tid < KSIZE) {
        float s = 0.f;
        #pragma unroll
        for (int k = 0; k < KSIZE; ++k) s += w[tid * KSIZE + k];
        sg[tid] = s;     // 1D taps = row sums of separable normalized 2D kernel (exact)
    }
    __syncthreads();
    for (int t = tid; t < 32 * 64; t += 256) {
        int r = t >> 6, k = t & 63, d = k - r;
        unsigned short v = 0;
        if (d >= 0 && d < KSIZE) v = (unsigned short)f2bf(sg[d]);
        G[t] = v;
    }
}

__global__ __launch_bounds__(256, 4) void ssim_main_kernel(
    const float* __restrict__ in, const float* __restrict__ tg,
    const unsigned short* __restrict__ G, float* __restrict__ partial)
{
    __shared__ __align__(16) unsigned short lds[LDS_TOT];
    __shared__ float swsum[4];

    const int tid = threadIdx.x;
    const int wave = tid >> 6, lane = tid & 63;
    const int m = lane & 15, q = lane >> 4;

    const int blk = blockIdx.x;
    const int plane = blk >> 8;
    const int t2 = blk & 255;
    const int x0 = (t2 & 15) * TILE - HALO;
    const int y0 = (t2 >> 4) * TILE - HALO;
    const float* __restrict__ inp = in + (size_t)plane * (HH * WW);
    const float* __restrict__ tgp = tg + (size_t)plane * (HH * WW);

    // ---- copy taps into LDS (swizzled, pitch 64) ----
    for (int t = tid; t < 32 * 64; t += 256) {
        int r = t >> 6, k = t & 63;
        lds[G_O + r * 64 + SWZ(r, k)] = G[t];
    }

    // ---- stage 54 rows x 64 cols as bf16 pairs (zero outside image) ----
    unsigned* ldsw = (unsigned*)lds;
    for (int t = tid; t < 54 * 32; t += 256) {
        int r = t >> 5, cd = t & 31;
        int gy = y0 + r, gx = x0 + cd * 2;
        float a0 = 0.f, a1 = 0.f, b0 = 0.f, b1 = 0.f;
        if (gy >= 0 && gy < HH) {
            const float* ri = inp + gy * WW;
            const float* rt = tgp + gy * WW;
            if ((unsigned)gx < (unsigned)WW)       { a0 = ri[gx];     b0 = rt[gx]; }
            if ((unsigned)(gx + 1) < (unsigned)WW) { a1 = ri[gx + 1]; b1 = rt[gx + 1]; }
        }
        ldsw[(SA_O >> 1) + r * 36 + cd] = f2bf(a0) | (f2bf(a1) << 16);
        ldsw[(SB_O >> 1) + r * 36 + cd] = f2bf(b0) | (f2bf(b1) << 16);
    }
    __syncthreads();

    // ---- h-pass (MFMA): wave = M-tile (image rows wave*16..+15) ----
    // hb[r][c] = sum_k S[r][k] * G[c][k]
    f32x4 acc[5][2];
    const f32x4 zz = {0.f, 0.f, 0.f, 0.f};
    #pragma unroll
    for (int ch = 0; ch < 5; ++ch) { acc[ch][0] = zz; acc[ch][1] = zz; }

    #pragma unroll
    for (int ks = 0; ks < 2; ++ks) {
        const int off = (wave * 16 + m) * SPITCH + ks * 32 + q * 8;
        uint4 ua = *(const uint4*)&lds[SA_O + off];
        uint4 ub = *(const uint4*)&lds[SB_O + off];
        uint4 uaa = bfmul4(ua, ua);
        uint4 ubb = bfmul4(ub, ub);
        uint4 uab = bfmul4(ua, ub);
        #pragma unroll
        for (int nc = 0; nc < 2; ++nc) {
            const int gr = nc * 16 + m;
            uint4 gf = *(const uint4*)&lds[G_O + gr * 64 + SWZ(gr, ks * 32 + q * 8)];
            acc[0][nc] = mfma16(ua,  gf, acc[0][nc]);
            acc[1][nc] = mfma16(ub,  gf, acc[1][nc]);
            acc[2][nc] = mfma16(uaa, gf, acc[2][nc]);
            acc[3][nc] = mfma16(ubb, gf, acc[3][nc]);
            acc[4][nc] = mfma16(uab, gf, acc[4][nc]);
        }
    }
    // D frag: col = lane&15 (+nc*16), row = q*4 + reg (+wave*16). hbT[ch][col][row], bf16.
    #pragma unroll
    for (int ch = 0; ch < 5; ++ch)
        #pragma unroll
        for (int nc = 0; nc < 2; ++nc) {
            f32x4 a = acc[ch][nc];
            uint2 pk;
            pk.x = f2bf(a[0]) | (f2bf(a[1]) << 16);
            pk.y = f2bf(a[2]) | (f2bf(a[3]) << 16);
            const int col = nc * 16 + m;
            const int rb = wave * 16 + q * 4;
            *(uint2*)&lds[HB_O + ch * HB_CH + col * 64 + SWZ(col, rb)] = pk;
        }
    __syncthreads();

    // ---- v-pass (MFMA): wave = output quadrant (mrow, nc2) ----
    // out[r][c] = sum_k G[r][k] * hb[k][c]; junk hb rows 54..63 hit G zeros.
    const int mrow = wave >> 1, nc2 = wave & 1;
    f32x4 av[5];
    #pragma unroll
    for (int ch = 0; ch < 5; ++ch) av[ch] = zz;

    #pragma unroll
    for (int ks = 0; ks < 2; ++ks) {
        const int ar = mrow * 16 + m;
        uint4 ga = *(const uint4*)&lds[G_O + ar * 64 + SWZ(ar, ks * 32 + q * 8)];
        #pragma unroll
        for (int ch = 0; ch < 5; ++ch) {
            const int col = nc2 * 16 + m;
            uint4 ub = *(const uint4*)&lds[HB_O + ch * HB_CH + col * 64 + SWZ(col, ks * 32 + q * 8)];
            av[ch] = mfma16(ga, ub, av[ch]);
        }
    }

    // ---- SSIM map on 4 px/lane + reduction ----
    float lsum = 0.f;
    #pragma unroll
    for (int i = 0; i < 4; ++i) {
        float vx = av[0][i], vt = av[1][i];
        float vxx = av[2][i], vtt = av[3][i], vxt = av[4][i];
        float m1s = vx * vx, m2s = vt * vt, m12 = vx * vt;
        float s1 = vxx - m1s, s2 = vtt - m2s, s12 = vxt - m12;
        float num = (2.f * m12 + C1V) * (2.f * s12 + C2V);
        float den = (m1s + m2s + C1V) * (s1 + s2 + C2V);
        lsum += num * __builtin_amdgcn_rcpf(den);   // den > 0 always
    }
    #pragma unroll
    for (int off = 32; off > 0; off >>= 1)
        lsum += __shfl_down(lsum, off, 64);
    if (lane == 0) swsum[wave] = lsum;
    __syncthreads();
    if (tid == 0)
        partial[blk] = swsum[0] + swsum[1] + swsum[2] + swsum[3];
}

__global__ __launch_bounds__(256) void ssim_final_kernel(
    const float* __restrict__ partial, float* __restrict__ out)
{
    __shared__ float swsum[4];
    const int tid = threadIdx.x;
    float s = 0.f;
    for (int i = tid; i < NBLK; i += 256) s += partial[i];
    #pragma unroll
    for (int off = 32; off > 0; off >>= 1)
        s += __shfl_down(s, off, 64);
    if ((tid & 63) == 0) swsum[tid >> 6] = s;
    __syncthreads();
    if (tid == 0)
        out[0] = 1.0f - (swsum[0] + swsum[1] + swsum[2] + swsum[3])
                        * (1.0f / ((float)NPLANES * HH * WW));
}

extern "C" void kernel_launch(void* const* d_in, const int* in_sizes, int n_in,
                              void* d_out, int out_size, void* d_ws, size_t ws_size,
                              hipStream_t stream) {
    const float* inp = (const float*)d_in[0];
    const float* tgt = (const float*)d_in[1];
    const float* wgt = (const float*)d_in[2];
    float* out = (float*)d_out;
    unsigned short* G = (unsigned short*)d_ws;              // 32*64 bf16 = 4 KB
    float* partial = (float*)((char*)d_ws + 4096);          // NBLK floats

    ssim_prep_kernel<<<1, 256, 0, stream>>>(wgt, G);
    ssim_main_kernel<<<NBLK, 256, 0, stream>>>(inp, tgt, G, partial);
    ssim_final_kernel<<<1, 256, 0, stream>>>(partial, out);
}